// Round 6
// baseline (412.633 us; speedup 1.0000x reference)
//
#include <hip/hip_runtime.h>
#include <math.h>

#define HID 2048
#define NB  2
#define SEQ 2048
#define NT  (NB*SEQ)   // 4096 tokens
#define NH  16
#define HD  128

typedef __attribute__((ext_vector_type(8))) _Float16       f16x8;  // 8 f16 (4 VGPRs)
typedef __attribute__((ext_vector_type(8))) unsigned short u16x8;  // raw 16B
typedef __attribute__((ext_vector_type(2))) __fp16         h16x2;  // cvt_pkrtz result
typedef __attribute__((ext_vector_type(4))) float          f32x4;  // 4 fp32 acc

// softmax scale folded with log2(e): scores in log2 domain -> exp2f.
#define QSCALE 0.12751742f   // (1/sqrt(128)) * log2(e)

__device__ __forceinline__ unsigned short f2h(float x) {   // fp32 -> fp16 (RNE)
    union { _Float16 h; unsigned short u; } c;
    c.h = (_Float16)x;
    return c.u;
}

// ---------------------------------------------------------------------------
// Cast: fp32 -> fp16, one dispatch for all 5 tensors (y selects; y=0 is X,
// y=1..4 the four weight matrices — W blocks beyond n4w early-return).
// ---------------------------------------------------------------------------
extern "C" __global__ __launch_bounds__(256)
void cast_all(const float* __restrict__ X,
              const float* __restrict__ w0, const float* __restrict__ w1,
              const float* __restrict__ w2, const float* __restrict__ w3,
              unsigned short* __restrict__ Xd,
              unsigned short* __restrict__ d0, unsigned short* __restrict__ d1,
              unsigned short* __restrict__ d2, unsigned short* __restrict__ d3,
              int n4x, int n4w)
{
    const int y = blockIdx.y;
    const float* __restrict__ src =
        (y==0) ? X : (y==1) ? w0 : (y==2) ? w1 : (y==3) ? w2 : w3;
    unsigned short* __restrict__ dst =
        (y==0) ? Xd : (y==1) ? d0 : (y==2) ? d1 : (y==3) ? d2 : d3;
    const int n4 = (y==0) ? n4x : n4w;
    const int i = blockIdx.x * 256 + threadIdx.x;
    if (i >= n4) return;
    const float4 x = ((const float4*)src)[i];
    ushort4 h;
    h.x = f2h(x.x); h.y = f2h(x.y); h.z = f2h(x.z); h.w = f2h(x.w);
    ((ushort4*)dst)[i] = h;
}

// ---------------------------------------------------------------------------
// Kernel 1: fused QKV projection, single-pass fp16 MFMA (proven 141-146 us).
// BK=64: A/B tiles 128x64 f16 (16 KB each), swizzle c^(row&7) applied on the
// GLOBAL source address (global_load_lds dest is lane-contiguous by HW).
//   Q -> [B,H,S,D] f16 pre-scaled by QSCALE
//   K -> [B,H,S,D] f16
//   V -> [B,H,D,S'] f16, s' sigma-permuted within 64-blocks:
//        pos = (s&~63) | ((s&15)<<2) | ((s>>4)&3)   (matches attn's P packing)
// ---------------------------------------------------------------------------
extern "C" __global__ __launch_bounds__(256)
void qkv_f16(const unsigned short* __restrict__ Xh,
             const unsigned short* __restrict__ Wqh,
             const unsigned short* __restrict__ Wkh,
             const unsigned short* __restrict__ Wvh,
             const float* __restrict__ bq, const float* __restrict__ bk,
             const float* __restrict__ bv,
             unsigned short* __restrict__ Qb, unsigned short* __restrict__ Kb,
             unsigned short* __restrict__ Vb)
{
    const int on0 = blockIdx.x * 128;
    const int tm0 = blockIdx.y * 128;
    const int which = blockIdx.z;
    const unsigned short* __restrict__ W = (which==0) ? Wqh : (which==1) ? Wkh : Wvh;
    const float* __restrict__ bias      = (which==0) ? bq  : (which==1) ? bk  : bv;

    __shared__ unsigned short Ah[8192], Bh[8192];   // 2 x 16 KB

    const int tid  = threadIdx.x;
    const int lane = tid & 63;
    const int w    = tid >> 6;
    const int wm   = (w & 1) * 64;
    const int wn   = (w >> 1) * 64;
    const int fr   = lane & 15;
    const int quad = lane >> 4;

    f32x4 acc[4][4];
    #pragma unroll
    for (int i = 0; i < 4; ++i)
        #pragma unroll
        for (int j = 0; j < 4; ++j)
            acc[i][j] = (f32x4){0.f, 0.f, 0.f, 0.f};

    for (int kb = 0; kb < HID/64; ++kb) {
        __syncthreads();
        const unsigned short* Asrc = Xh + (size_t)tm0*HID + kb*64;
        const unsigned short* Bsrc = W  + (size_t)on0*HID + kb*64;
        #pragma unroll
        for (int r = 0; r < 4; ++r) {
            const int p   = (r*4 + w)*64 + lane;     // chunk 0..1023
            const int row = p >> 3;
            const int c   = (p & 7) ^ (row & 7);
            __builtin_amdgcn_global_load_lds(
                (const __attribute__((address_space(1))) void*)(Asrc + (size_t)row*HID + c*8),
                (__attribute__((address_space(3))) void*)(Ah + (r*4 + w)*512), 16, 0, 0);
            __builtin_amdgcn_global_load_lds(
                (const __attribute__((address_space(1))) void*)(Bsrc + (size_t)row*HID + c*8),
                (__attribute__((address_space(3))) void*)(Bh + (r*4 + w)*512), 16, 0, 0);
        }
        __syncthreads();

        #pragma unroll
        for (int kk = 0; kk < 2; ++kk) {
            f16x8 a[4], b[4];
            #pragma unroll
            for (int i = 0; i < 4; ++i) {
                const int ra = wm + i*16 + fr;
                a[i] = *(const f16x8*)(Ah + (ra*8 + ((kk*4 + quad) ^ (ra & 7)))*8);
                const int rb = wn + i*16 + fr;
                b[i] = *(const f16x8*)(Bh + (rb*8 + ((kk*4 + quad) ^ (rb & 7)))*8);
            }
            #pragma unroll
            for (int i = 0; i < 4; ++i)
                #pragma unroll
                for (int j = 0; j < 4; ++j)
                    acc[i][j] = __builtin_amdgcn_mfma_f32_16x16x32_f16(a[i], b[j], acc[i][j], 0, 0, 0);
        }
    }

    // epilogue: C layout col=lane&15, row=quad*4+reg
    const int col_l = fr;
    if (which == 2) {
        #pragma unroll
        for (int j = 0; j < 4; ++j) {
            const int o = on0 + wn + j*16 + col_l;
            const float bb = bias[o];
            const int h = o >> 7, d = o & (HD-1);
            #pragma unroll
            for (int i = 0; i < 4; ++i)
                #pragma unroll
                for (int rg = 0; rg < 4; ++rg) {
                    const int t = tm0 + wm + i*16 + quad*4 + rg;
                    const int b = t >> 11, s = t & (SEQ-1);
                    const int pos = (s & ~63) | (((s & 15) << 2) | ((s >> 4) & 3));
                    Vb[((size_t)(b*NH + h)*HD + d)*SEQ + pos] = f2h(acc[i][j][rg] + bb);
                }
        }
    } else {
        const float sc = (which == 0) ? QSCALE : 1.0f;
        unsigned short* __restrict__ dstp = (which == 0) ? Qb : Kb;
        #pragma unroll
        for (int j = 0; j < 4; ++j) {
            const int o = on0 + wn + j*16 + col_l;
            const float bb = bias[o];
            const int h = o >> 7, d = o & (HD-1);
            #pragma unroll
            for (int i = 0; i < 4; ++i)
                #pragma unroll
                for (int rg = 0; rg < 4; ++rg) {
                    const int t = tm0 + wm + i*16 + quad*4 + rg;
                    const int b = t >> 11, s = t & (SEQ-1);
                    dstp[((size_t)(b*NH + h)*SEQ + s)*HD + d] =
                        f2h((acc[i][j][rg] + bb) * sc);
                }
        }
    }
}

// ---------------------------------------------------------------------------
// Kernel 2: MFMA flash attention (512 thr / 8 waves, 16 Q-rows/wave).
// v4: T14 async-STAGE split — K/V tile t+1 is loaded into REGISTERS (plain
// global_load_dwordx4, swizzle applied on the reg-load source, LDS dest
// linear) issued BEFORE compute of tile t; after the post-compute barrier the
// regs are ds_write_b128'd (compiler inserts the vmcnt wait).  HBM latency
// (~600cy) hides under QK+softmax+PV (>1000cy).  Replaces the serial
// global_load_lds-between-barriers staging.  Same LDS (50 KB), 2 barriers/it.
// Output token-major Of[t][HID].
// ---------------------------------------------------------------------------
#define PS_STRIDE 72   // 64 + 8 pad; 72 ushorts = 144 B = 9*16 B

extern "C" __global__ __launch_bounds__(512, 4)
void attn_mfma(const unsigned short* __restrict__ Qg, const unsigned short* __restrict__ Kg,
               const unsigned short* __restrict__ Vtg, unsigned short* __restrict__ Of)
{
    const int L  = blockIdx.x;
    const int q0 = (L >> 5) * 128;
    const int bh = ((L & 7) << 2) | ((L >> 3) & 3);
    const unsigned short* __restrict__ Qp = Qg  + (size_t)bh * SEQ * HD;
    const unsigned short* __restrict__ Kp = Kg  + (size_t)bh * SEQ * HD;
    const unsigned short* __restrict__ Vp = Vtg + (size_t)bh * HD * SEQ;

    __shared__ alignas(16) unsigned short Ks[64*128];          // 16 KB [s][d]
    __shared__ alignas(16) unsigned short Vts[128*64];         // 16 KB [d][s']
    __shared__ alignas(16) unsigned short Ps[8][16*PS_STRIDE]; // 18 KB

    const int tid  = threadIdx.x;
    const int lane = tid & 63;
    const int w    = tid >> 6;       // 0..7
    const int fr   = lane & 15;
    const int quad = lane >> 4;

    f16x8 qf[4];
    #pragma unroll
    for (int c = 0; c < 4; ++c)
        qf[c] = *(const f16x8*)(Qp + (size_t)(q0 + w*16 + fr)*HD + c*32 + quad*8);

    f32x4 accO[8];
    #pragma unroll
    for (int n = 0; n < 8; ++n)
        accO[n] = (f32x4){0.f, 0.f, 0.f, 0.f};
    float lp[4] = {};

    // per-thread staging state (16 VGPR)
    u16x8 kreg[2], vreg[2];

    // load addressing (constant per thread)
    int kp_[2], krow_[2], kc_[2];       // K: [s][d] with c^(row&15)
    int vp_[2], vrow_[2], vc_[2];       // V: [d][s'] with c^(row&7)
    #pragma unroll
    for (int r = 0; r < 2; ++r) {
        const int p = (r*8 + w)*64 + lane;   // 0..1023
        kp_[r] = p; krow_[r] = p >> 4; kc_[r] = (p & 15) ^ (krow_[r] & 15);
        vp_[r] = p; vrow_[r] = p >> 3; vc_[r] = (p & 7) ^ (vrow_[r] & 7);
    }

#define ISSUE_KV(kt_) do {                                                     \
    const unsigned short* _Kt = Kp + (size_t)(kt_)*64*HD;                      \
    _Pragma("unroll")                                                          \
    for (int _r = 0; _r < 2; ++_r)                                             \
        kreg[_r] = *(const u16x8*)(_Kt + (size_t)krow_[_r]*HD + kc_[_r]*8);    \
    _Pragma("unroll")                                                          \
    for (int _r = 0; _r < 2; ++_r)                                             \
        vreg[_r] = *(const u16x8*)(Vp + (size_t)vrow_[_r]*SEQ + (kt_)*64 + vc_[_r]*8); \
    } while (0)

#define WRITE_KV() do {                                                        \
    _Pragma("unroll")                                                          \
    for (int _r = 0; _r < 2; ++_r)                                             \
        *(u16x8*)(Ks + kp_[_r]*8) = kreg[_r];                                  \
    _Pragma("unroll")                                                          \
    for (int _r = 0; _r < 2; ++_r)                                             \
        *(u16x8*)(Vts + vp_[_r]*8) = vreg[_r];                                 \
    } while (0)

    // prologue: stage tile 0
    ISSUE_KV(0);
    WRITE_KV();          // compiler inserts vmcnt(0) before the ds_writes
    __syncthreads();

    for (int kt = 0; kt < SEQ/64; ++kt) {
        // ---- issue next-tile loads (latency hides under compute) ----
        if (kt + 1 < SEQ/64) ISSUE_KV(kt + 1);

        // ---- S = Q K^T (log2 domain) ----
        f32x4 accS[4];
        #pragma unroll
        for (int n = 0; n < 4; ++n)
            accS[n] = (f32x4){0.f, 0.f, 0.f, 0.f};
        #pragma unroll
        for (int c = 0; c < 4; ++c) {
            f16x8 bf[4];
            #pragma unroll
            for (int n = 0; n < 4; ++n)
                bf[n] = *(const f16x8*)(Ks + (n*16 + fr)*128 + ((c*4 + quad) ^ fr)*8);
            __builtin_amdgcn_s_setprio(1);
            #pragma unroll
            for (int n = 0; n < 4; ++n)
                accS[n] = __builtin_amdgcn_mfma_f32_16x16x32_f16(
                    qf[c], bf[n], accS[n], 0, 0, 0);
            __builtin_amdgcn_s_setprio(0);
        }

        // ---- P = exp2(S); pack 4 keys/write at sigma-permuted positions ----
        #pragma unroll
        for (int rg = 0; rg < 4; ++rg) {
            float p0 = exp2f(accS[0][rg]);
            float p1 = exp2f(accS[1][rg]);
            float p2 = exp2f(accS[2][rg]);
            float p3 = exp2f(accS[3][rg]);
            lp[rg] += (p0 + p1) + (p2 + p3);
            union { h16x2 h[2]; ushort4 u4; } pk;
            pk.h[0] = __builtin_amdgcn_cvt_pkrtz(p0, p1);
            pk.h[1] = __builtin_amdgcn_cvt_pkrtz(p2, p3);
            *(ushort4*)(&Ps[w][(quad*4 + rg)*PS_STRIDE + fr*4]) = pk.u4;
        }

        // ---- O += P @ V (keys in sigma order on both sides) ----
        #pragma unroll
        for (int cc = 0; cc < 2; ++cc) {
            f16x8 pf = *(const f16x8*)(&Ps[w][fr*PS_STRIDE + cc*32 + quad*8]);
            f16x8 vf[8];
            #pragma unroll
            for (int n = 0; n < 8; ++n)
                vf[n] = *(const f16x8*)(Vts + (n*16 + fr)*64 + ((cc*4 + quad) ^ (fr & 7))*8);
            __builtin_amdgcn_s_setprio(1);
            #pragma unroll
            for (int n = 0; n < 8; ++n)
                accO[n] = __builtin_amdgcn_mfma_f32_16x16x32_f16(
                    pf, vf[n], accO[n], 0, 0, 0);
            __builtin_amdgcn_s_setprio(0);
        }

        // ---- rotate LDS buffer: all waves done reading, then write t+1 ----
        __syncthreads();
        if (kt + 1 < SEQ/64) WRITE_KV();
        __syncthreads();
    }
#undef ISSUE_KV
#undef WRITE_KV

    // ---- epilogue: reduce l across the 16 lanes sharing each row ----
    float inv[4];
    #pragma unroll
    for (int rg = 0; rg < 4; ++rg) {
        float l = lp[rg];
        l += __shfl_xor(l, 1);
        l += __shfl_xor(l, 2);
        l += __shfl_xor(l, 4);
        l += __shfl_xor(l, 8);
        inv[rg] = 1.0f / l;
    }
    const int bb_ = bh >> 4;         // batch
    const int hh_ = bh & (NH - 1);   // head
    #pragma unroll
    for (int n = 0; n < 8; ++n) {
        const int d = n*16 + fr;
        #pragma unroll
        for (int rg = 0; rg < 4; ++rg) {
            const int s = q0 + w*16 + quad*4 + rg;
            // token-major: Of[(b*SEQ+s)][h*HD + d]
            Of[((size_t)(bb_*SEQ + s))*HID + hh_*HD + d] = f2h(accO[n][rg] * inv[rg]);
        }
    }
}

// ---------------------------------------------------------------------------
// Kernel 3: output projection.  512 threads / 8 waves per 128x128 tile
// (each wave owns 64x32, acc[4][2]).  A is token-major [t][HID] f16 (same
// read path as qkv's X).
// ---------------------------------------------------------------------------
extern "C" __global__ __launch_bounds__(512)
void oproj_f16(const unsigned short* __restrict__ Af,
               const unsigned short* __restrict__ Woh,
               const float* __restrict__ bo, float* __restrict__ Y)
{
    const int on0 = blockIdx.x * 128;
    const int tm0 = blockIdx.y * 128;

    __shared__ unsigned short Ah[8192], Bh[8192];   // 2 x 16 KB

    const int tid  = threadIdx.x;
    const int lane = tid & 63;
    const int w    = tid >> 6;      // 0..7
    const int wm   = (w >> 2) * 64; // 0,64
    const int wn   = (w & 3) * 32;  // 0,32,64,96
    const int fr   = lane & 15;
    const int quad = lane >> 4;

    f32x4 acc[4][2];
    #pragma unroll
    for (int i = 0; i < 4; ++i)
        #pragma unroll
        for (int j = 0; j < 2; ++j)
            acc[i][j] = (f32x4){0.f, 0.f, 0.f, 0.f};

    for (int kb = 0; kb < HID/64; ++kb) {
        __syncthreads();
        const unsigned short* Asrc = Af  + (size_t)tm0*HID + kb*64;
        const unsigned short* Bsrc = Woh + (size_t)on0*HID + kb*64;
        #pragma unroll
        for (int r = 0; r < 2; ++r) {
            const int p   = r*512 + tid;    // chunk 0..1023
            const int row = p >> 3;
            const int c   = (p & 7) ^ (row & 7);
            __builtin_amdgcn_global_load_lds(
                (const __attribute__((address_space(1))) void*)(Asrc + (size_t)row*HID + c*8),
                (__attribute__((address_space(3))) void*)(Ah + p*8), 16, 0, 0);
            __builtin_amdgcn_global_load_lds(
                (const __attribute__((address_space(1))) void*)(Bsrc + (size_t)row*HID + c*8),
                (__attribute__((address_space(3))) void*)(Bh + p*8), 16, 0, 0);
        }
        __syncthreads();

        #pragma unroll
        for (int kk = 0; kk < 2; ++kk) {
            f16x8 a[4], b[2];
            #pragma unroll
            for (int i = 0; i < 4; ++i) {
                const int ra = wm + i*16 + fr;
                a[i] = *(const f16x8*)(Ah + (ra*8 + ((kk*4 + quad) ^ (ra & 7)))*8);
            }
            #pragma unroll
            for (int j = 0; j < 2; ++j) {
                const int rb = wn + j*16 + fr;
                b[j] = *(const f16x8*)(Bh + (rb*8 + ((kk*4 + quad) ^ (rb & 7)))*8);
            }
            #pragma unroll
            for (int i = 0; i < 4; ++i)
                #pragma unroll
                for (int j = 0; j < 2; ++j)
                    acc[i][j] = __builtin_amdgcn_mfma_f32_16x16x32_f16(a[i], b[j], acc[i][j], 0, 0, 0);
        }
    }

    #pragma unroll
    for (int j = 0; j < 2; ++j) {
        const int o = on0 + wn + j*16 + fr;
        const float bb = bo[o];
        #pragma unroll
        for (int i = 0; i < 4; ++i)
            #pragma unroll
            for (int rg = 0; rg < 4; ++rg) {
                const int t = tm0 + wm + i*16 + quad*4 + rg;
                Y[(size_t)t*HID + o] = acc[i][j][rg] + bb;
            }
    }
}

// ---------------------------------------------------------------------------
// Launch.  Workspace (ushort units, 117 MB):
//   Qb,Kb f16 [B,H,S,D]; Vb f16 [B,H,D,S'] (sigma-permuted)
//   Of f16 [t][HID] token-major (attn output)
//   Xh f16; Wq/Wk/Wv/Wo f16
// ---------------------------------------------------------------------------
extern "C" void kernel_launch(void* const* d_in, const int* in_sizes, int n_in,
                              void* d_out, int out_size, void* d_ws, size_t ws_size,
                              hipStream_t stream)
{
    const float* X  = (const float*)d_in[0];
    const float* wq = (const float*)d_in[1];
    const float* bq = (const float*)d_in[2];
    const float* wk = (const float*)d_in[3];
    const float* bk = (const float*)d_in[4];
    const float* wv = (const float*)d_in[5];
    const float* bv = (const float*)d_in[6];
    const float* wo = (const float*)d_in[7];
    const float* bo = (const float*)d_in[8];
    float* Y = (float*)d_out;

    const size_t F  = (size_t)NT * HID;    // 8,388,608
    const size_t Wn = (size_t)HID * HID;   // 4,194,304

    unsigned short* Qb  = (unsigned short*)d_ws;
    unsigned short* Kb  = Qb  + F;
    unsigned short* Vb  = Kb  + F;     // [B,H,D,S'] permuted
    unsigned short* Of  = Vb  + F;     // token-major [t][HID]
    unsigned short* Xh  = Of  + F;
    unsigned short* Wqh = Xh  + F;
    unsigned short* Wkh = Wqh + Wn;
    unsigned short* Wvh = Wkh + Wn;
    unsigned short* Woh = Wvh + Wn;

    const int n4x = (int)(F/4);    // 2,097,152
    const int n4w = (int)(Wn/4);   // 1,048,576

    cast_all<<<dim3((n4x + 255)/256, 5), 256, 0, stream>>>(
        X, wq, wk, wv, wo, Xh, Wqh, Wkh, Wvh, Woh, n4x, n4w);

    qkv_f16<<<dim3(HID/128, NT/128, 3), 256, 0, stream>>>(
        Xh, Wqh, Wkh, Wvh, bq, bk, bv, Qb, Kb, Vb);

    attn_mfma<<<dim3(512, 1, 1), 512, 0, stream>>>(Qb, Kb, Vb, Of);

    oproj_f16<<<dim3(HID/128, NT/128), 512, 0, stream>>>(Of, Woh, bo, Y);
}

// Round 7
// 396.492 us; speedup vs baseline: 1.0407x; 1.0407x over previous
//
#include <hip/hip_runtime.h>
#include <math.h>

#define HID 2048
#define NB  2
#define SEQ 2048
#define NT  (NB*SEQ)   // 4096 tokens
#define NH  16
#define HD  128

typedef __attribute__((ext_vector_type(8))) _Float16       f16x8;  // 8 f16 (4 VGPRs)
typedef __attribute__((ext_vector_type(2))) __fp16         h16x2;  // cvt_pkrtz result
typedef __attribute__((ext_vector_type(4))) float          f32x4;  // 4 fp32 acc

// softmax scale folded with log2(e): scores in log2 domain -> exp2f.
#define QSCALE 0.12751742f   // (1/sqrt(128)) * log2(e)

__device__ __forceinline__ unsigned short f2h(float x) {   // fp32 -> fp16 (RNE)
    union { _Float16 h; unsigned short u; } c;
    c.h = (_Float16)x;
    return c.u;
}

// ---------------------------------------------------------------------------
// Cast: fp32 -> fp16, one dispatch for all 5 tensors (y selects; y=0 is X,
// y=1..4 the four weight matrices — W blocks beyond n4w early-return).
// ---------------------------------------------------------------------------
extern "C" __global__ __launch_bounds__(256)
void cast_all(const float* __restrict__ X,
              const float* __restrict__ w0, const float* __restrict__ w1,
              const float* __restrict__ w2, const float* __restrict__ w3,
              unsigned short* __restrict__ Xd,
              unsigned short* __restrict__ d0, unsigned short* __restrict__ d1,
              unsigned short* __restrict__ d2, unsigned short* __restrict__ d3,
              int n4x, int n4w)
{
    const int y = blockIdx.y;
    const float* __restrict__ src =
        (y==0) ? X : (y==1) ? w0 : (y==2) ? w1 : (y==3) ? w2 : w3;
    unsigned short* __restrict__ dst =
        (y==0) ? Xd : (y==1) ? d0 : (y==2) ? d1 : (y==3) ? d2 : d3;
    const int n4 = (y==0) ? n4x : n4w;
    const int i = blockIdx.x * 256 + threadIdx.x;
    if (i >= n4) return;
    const float4 x = ((const float4*)src)[i];
    ushort4 h;
    h.x = f2h(x.x); h.y = f2h(x.y); h.z = f2h(x.z); h.w = f2h(x.w);
    ((ushort4*)dst)[i] = h;
}

// ---------------------------------------------------------------------------
// Kernel 1: fused QKV projection, single-pass fp16 MFMA (proven 139-146 us).
// BK=64: A/B tiles 128x64 f16 (16 KB each), swizzle c^(row&7) applied on the
// GLOBAL source address (global_load_lds dest is lane-contiguous by HW).
//   Q -> [B,H,S,D] f16 pre-scaled by QSCALE
//   K -> [B,H,S,D] f16
//   V -> [B,H,D,S'] f16, s' sigma-permuted within 64-blocks:
//        pos = (s&~63) | ((s&15)<<2) | ((s>>4)&3)   (matches attn's P packing)
// ---------------------------------------------------------------------------
extern "C" __global__ __launch_bounds__(256)
void qkv_f16(const unsigned short* __restrict__ Xh,
             const unsigned short* __restrict__ Wqh,
             const unsigned short* __restrict__ Wkh,
             const unsigned short* __restrict__ Wvh,
             const float* __restrict__ bq, const float* __restrict__ bk,
             const float* __restrict__ bv,
             unsigned short* __restrict__ Qb, unsigned short* __restrict__ Kb,
             unsigned short* __restrict__ Vb)
{
    const int on0 = blockIdx.x * 128;
    const int tm0 = blockIdx.y * 128;
    const int which = blockIdx.z;
    const unsigned short* __restrict__ W = (which==0) ? Wqh : (which==1) ? Wkh : Wvh;
    const float* __restrict__ bias      = (which==0) ? bq  : (which==1) ? bk  : bv;

    __shared__ unsigned short Ah[8192], Bh[8192];   // 2 x 16 KB

    const int tid  = threadIdx.x;
    const int lane = tid & 63;
    const int w    = tid >> 6;
    const int wm   = (w & 1) * 64;
    const int wn   = (w >> 1) * 64;
    const int fr   = lane & 15;
    const int quad = lane >> 4;

    f32x4 acc[4][4];
    #pragma unroll
    for (int i = 0; i < 4; ++i)
        #pragma unroll
        for (int j = 0; j < 4; ++j)
            acc[i][j] = (f32x4){0.f, 0.f, 0.f, 0.f};

    for (int kb = 0; kb < HID/64; ++kb) {
        __syncthreads();
        const unsigned short* Asrc = Xh + (size_t)tm0*HID + kb*64;
        const unsigned short* Bsrc = W  + (size_t)on0*HID + kb*64;
        #pragma unroll
        for (int r = 0; r < 4; ++r) {
            const int p   = (r*4 + w)*64 + lane;     // chunk 0..1023
            const int row = p >> 3;
            const int c   = (p & 7) ^ (row & 7);
            __builtin_amdgcn_global_load_lds(
                (const __attribute__((address_space(1))) void*)(Asrc + (size_t)row*HID + c*8),
                (__attribute__((address_space(3))) void*)(Ah + (r*4 + w)*512), 16, 0, 0);
            __builtin_amdgcn_global_load_lds(
                (const __attribute__((address_space(1))) void*)(Bsrc + (size_t)row*HID + c*8),
                (__attribute__((address_space(3))) void*)(Bh + (r*4 + w)*512), 16, 0, 0);
        }
        __syncthreads();

        #pragma unroll
        for (int kk = 0; kk < 2; ++kk) {
            f16x8 a[4], b[4];
            #pragma unroll
            for (int i = 0; i < 4; ++i) {
                const int ra = wm + i*16 + fr;
                a[i] = *(const f16x8*)(Ah + (ra*8 + ((kk*4 + quad) ^ (ra & 7)))*8);
                const int rb = wn + i*16 + fr;
                b[i] = *(const f16x8*)(Bh + (rb*8 + ((kk*4 + quad) ^ (rb & 7)))*8);
            }
            #pragma unroll
            for (int i = 0; i < 4; ++i)
                #pragma unroll
                for (int j = 0; j < 4; ++j)
                    acc[i][j] = __builtin_amdgcn_mfma_f32_16x16x32_f16(a[i], b[j], acc[i][j], 0, 0, 0);
        }
    }

    // epilogue: C layout col=lane&15, row=quad*4+reg
    const int col_l = fr;
    if (which == 2) {
        #pragma unroll
        for (int j = 0; j < 4; ++j) {
            const int o = on0 + wn + j*16 + col_l;
            const float bb = bias[o];
            const int h = o >> 7, d = o & (HD-1);
            #pragma unroll
            for (int i = 0; i < 4; ++i)
                #pragma unroll
                for (int rg = 0; rg < 4; ++rg) {
                    const int t = tm0 + wm + i*16 + quad*4 + rg;
                    const int b = t >> 11, s = t & (SEQ-1);
                    const int pos = (s & ~63) | (((s & 15) << 2) | ((s >> 4) & 3));
                    Vb[((size_t)(b*NH + h)*HD + d)*SEQ + pos] = f2h(acc[i][j][rg] + bb);
                }
        }
    } else {
        const float sc = (which == 0) ? QSCALE : 1.0f;
        unsigned short* __restrict__ dstp = (which == 0) ? Qb : Kb;
        #pragma unroll
        for (int j = 0; j < 4; ++j) {
            const int o = on0 + wn + j*16 + col_l;
            const float bb = bias[o];
            const int h = o >> 7, d = o & (HD-1);
            #pragma unroll
            for (int i = 0; i < 4; ++i)
                #pragma unroll
                for (int rg = 0; rg < 4; ++rg) {
                    const int t = tm0 + wm + i*16 + quad*4 + rg;
                    const int b = t >> 11, s = t & (SEQ-1);
                    dstp[((size_t)(b*NH + h)*SEQ + s)*HD + d] =
                        f2h((acc[i][j][rg] + bb) * sc);
                }
        }
    }
}

// ---------------------------------------------------------------------------
// Kernel 2: MFMA flash attention (512 thr / 8 waves, 16 Q-rows/wave,
// cvt_pkrtz P-pack, setprio MFMA clusters).  Output token-major Of[t][HID].
// R6 post-mortem: reg-staged T14 variant regressed (+10 us) — reverted to
// the proven global_load_lds staging (reg-staging costs more than the
// latency it hides when gload_lds is available; m151).
// ---------------------------------------------------------------------------
#define PS_STRIDE 72   // 64 + 8 pad; 72 ushorts = 144 B = 9*16 B

extern "C" __global__ __launch_bounds__(512, 4)
void attn_mfma(const unsigned short* __restrict__ Qg, const unsigned short* __restrict__ Kg,
               const unsigned short* __restrict__ Vtg, unsigned short* __restrict__ Of)
{
    const int L  = blockIdx.x;
    const int q0 = (L >> 5) * 128;
    const int bh = ((L & 7) << 2) | ((L >> 3) & 3);
    const unsigned short* __restrict__ Qp = Qg  + (size_t)bh * SEQ * HD;
    const unsigned short* __restrict__ Kp = Kg  + (size_t)bh * SEQ * HD;
    const unsigned short* __restrict__ Vp = Vtg + (size_t)bh * HD * SEQ;

    __shared__ alignas(16) unsigned short Ks[64*128];          // 16 KB [s][d]
    __shared__ alignas(16) unsigned short Vts[128*64];         // 16 KB [d][s']
    __shared__ alignas(16) unsigned short Ps[8][16*PS_STRIDE]; // 18 KB

    const int tid  = threadIdx.x;
    const int lane = tid & 63;
    const int w    = tid >> 6;       // 0..7
    const int fr   = lane & 15;
    const int quad = lane >> 4;

    f16x8 qf[4];
    #pragma unroll
    for (int c = 0; c < 4; ++c)
        qf[c] = *(const f16x8*)(Qp + (size_t)(q0 + w*16 + fr)*HD + c*32 + quad*8);

    f32x4 accO[8];
    #pragma unroll
    for (int n = 0; n < 8; ++n)
        accO[n] = (f32x4){0.f, 0.f, 0.f, 0.f};
    float lp[4] = {};

    for (int kt = 0; kt < SEQ/64; ++kt) {
        __syncthreads();                       // prior reads of Ks/Vts done
        {
            const unsigned short* Kt = Kp + (size_t)kt*64*HD;
            #pragma unroll
            for (int r = 0; r < 2; ++r) {
                const int p   = (r*8 + w)*64 + lane;   // 0..1023
                const int row = p >> 4;
                const int c   = (p & 15) ^ (row & 15);
                __builtin_amdgcn_global_load_lds(
                    (const __attribute__((address_space(1))) void*)(Kt + (size_t)row*HD + c*8),
                    (__attribute__((address_space(3))) void*)(Ks + (r*8 + w)*512), 16, 0, 0);
            }
            #pragma unroll
            for (int r = 0; r < 2; ++r) {
                const int p   = (r*8 + w)*64 + lane;
                const int row = p >> 3;                // d 0..127
                const int c   = (p & 7) ^ (row & 7);
                __builtin_amdgcn_global_load_lds(
                    (const __attribute__((address_space(1))) void*)(Vp + (size_t)row*SEQ + kt*64 + c*8),
                    (__attribute__((address_space(3))) void*)(Vts + (r*8 + w)*512), 16, 0, 0);
            }
        }
        __syncthreads();                       // staging complete

        // ---- S = Q K^T (log2 domain) ----
        f32x4 accS[4];
        #pragma unroll
        for (int n = 0; n < 4; ++n)
            accS[n] = (f32x4){0.f, 0.f, 0.f, 0.f};
        #pragma unroll
        for (int c = 0; c < 4; ++c) {
            f16x8 bf[4];
            #pragma unroll
            for (int n = 0; n < 4; ++n)
                bf[n] = *(const f16x8*)(Ks + (n*16 + fr)*128 + ((c*4 + quad) ^ fr)*8);
            __builtin_amdgcn_s_setprio(1);
            #pragma unroll
            for (int n = 0; n < 4; ++n)
                accS[n] = __builtin_amdgcn_mfma_f32_16x16x32_f16(
                    qf[c], bf[n], accS[n], 0, 0, 0);
            __builtin_amdgcn_s_setprio(0);
        }

        // ---- P = exp2(S); pack 4 keys/write at sigma-permuted positions ----
        #pragma unroll
        for (int rg = 0; rg < 4; ++rg) {
            float p0 = exp2f(accS[0][rg]);
            float p1 = exp2f(accS[1][rg]);
            float p2 = exp2f(accS[2][rg]);
            float p3 = exp2f(accS[3][rg]);
            lp[rg] += (p0 + p1) + (p2 + p3);
            union { h16x2 h[2]; ushort4 u4; } pk;
            pk.h[0] = __builtin_amdgcn_cvt_pkrtz(p0, p1);
            pk.h[1] = __builtin_amdgcn_cvt_pkrtz(p2, p3);
            *(ushort4*)(&Ps[w][(quad*4 + rg)*PS_STRIDE + fr*4]) = pk.u4;
        }

        // ---- O += P @ V (keys in sigma order on both sides) ----
        #pragma unroll
        for (int cc = 0; cc < 2; ++cc) {
            f16x8 pf = *(const f16x8*)(&Ps[w][fr*PS_STRIDE + cc*32 + quad*8]);
            f16x8 vf[8];
            #pragma unroll
            for (int n = 0; n < 8; ++n)
                vf[n] = *(const f16x8*)(Vts + (n*16 + fr)*64 + ((cc*4 + quad) ^ (fr & 7))*8);
            __builtin_amdgcn_s_setprio(1);
            #pragma unroll
            for (int n = 0; n < 8; ++n)
                accO[n] = __builtin_amdgcn_mfma_f32_16x16x32_f16(
                    pf, vf[n], accO[n], 0, 0, 0);
            __builtin_amdgcn_s_setprio(0);
        }
    }

    // ---- epilogue: reduce l across the 16 lanes sharing each row ----
    float inv[4];
    #pragma unroll
    for (int rg = 0; rg < 4; ++rg) {
        float l = lp[rg];
        l += __shfl_xor(l, 1);
        l += __shfl_xor(l, 2);
        l += __shfl_xor(l, 4);
        l += __shfl_xor(l, 8);
        inv[rg] = 1.0f / l;
    }
    const int bb_ = bh >> 4;         // batch
    const int hh_ = bh & (NH - 1);   // head
    #pragma unroll
    for (int n = 0; n < 8; ++n) {
        const int d = n*16 + fr;
        #pragma unroll
        for (int rg = 0; rg < 4; ++rg) {
            const int s = q0 + w*16 + quad*4 + rg;
            // token-major: Of[(b*SEQ+s)][h*HD + d]
            Of[((size_t)(bb_*SEQ + s))*HID + hh_*HD + d] = f2h(accO[n][rg] * inv[rg]);
        }
    }
}

// ---------------------------------------------------------------------------
// Kernel 3: output projection.  v5: BM=64 x BN=128 tile, 256 threads
// (4 waves x 32x64, acc[2][4]) -> grid (16,64) = 1024 blocks, 24 KB LDS ->
// 4+ resident blocks/CU.  The 512-block 2-resident version had the least
// barrier-drain cover in the chain (m114: other blocks' waves fill the
// vmcnt(0)+barrier stall); same MFMA:ds_read ratio, same swizzle/paths.
// A is token-major [t][HID] f16.
// ---------------------------------------------------------------------------
extern "C" __global__ __launch_bounds__(256)
void oproj_f16(const unsigned short* __restrict__ Af,
               const unsigned short* __restrict__ Woh,
               const float* __restrict__ bo, float* __restrict__ Y)
{
    const int on0 = blockIdx.x * 128;
    const int tm0 = blockIdx.y * 64;

    __shared__ unsigned short Ah[4096], Bh[8192];   // 8 KB + 16 KB

    const int tid  = threadIdx.x;
    const int lane = tid & 63;
    const int w    = tid >> 6;      // 0..3
    const int wm   = (w & 1) * 32;  // 0,32
    const int wn   = (w >> 1) * 64; // 0,64
    const int fr   = lane & 15;
    const int quad = lane >> 4;

    f32x4 acc[2][4];
    #pragma unroll
    for (int i = 0; i < 2; ++i)
        #pragma unroll
        for (int j = 0; j < 4; ++j)
            acc[i][j] = (f32x4){0.f, 0.f, 0.f, 0.f};

    for (int kb = 0; kb < HID/64; ++kb) {
        __syncthreads();
        const unsigned short* Asrc = Af  + (size_t)tm0*HID + kb*64;
        const unsigned short* Bsrc = Woh + (size_t)on0*HID + kb*64;
        #pragma unroll
        for (int r = 0; r < 2; ++r) {       // A: 64x64 = 512 chunks
            const int p   = r*256 + tid;
            const int row = p >> 3;
            const int c   = (p & 7) ^ (row & 7);
            __builtin_amdgcn_global_load_lds(
                (const __attribute__((address_space(1))) void*)(Asrc + (size_t)row*HID + c*8),
                (__attribute__((address_space(3))) void*)(Ah + p*8), 16, 0, 0);
        }
        #pragma unroll
        for (int r = 0; r < 4; ++r) {       // B: 128x64 = 1024 chunks
            const int p   = r*256 + tid;
            const int row = p >> 3;
            const int c   = (p & 7) ^ (row & 7);
            __builtin_amdgcn_global_load_lds(
                (const __attribute__((address_space(1))) void*)(Bsrc + (size_t)row*HID + c*8),
                (__attribute__((address_space(3))) void*)(Bh + p*8), 16, 0, 0);
        }
        __syncthreads();

        #pragma unroll
        for (int kk = 0; kk < 2; ++kk) {
            f16x8 a[2], b[4];
            #pragma unroll
            for (int i = 0; i < 2; ++i) {
                const int ra = wm + i*16 + fr;
                a[i] = *(const f16x8*)(Ah + (ra*8 + ((kk*4 + quad) ^ (ra & 7)))*8);
            }
            #pragma unroll
            for (int j = 0; j < 4; ++j) {
                const int rb = wn + j*16 + fr;
                b[j] = *(const f16x8*)(Bh + (rb*8 + ((kk*4 + quad) ^ (rb & 7)))*8);
            }
            #pragma unroll
            for (int i = 0; i < 2; ++i)
                #pragma unroll
                for (int j = 0; j < 4; ++j)
                    acc[i][j] = __builtin_amdgcn_mfma_f32_16x16x32_f16(a[i], b[j], acc[i][j], 0, 0, 0);
        }
    }

    #pragma unroll
    for (int j = 0; j < 4; ++j) {
        const int o = on0 + wn + j*16 + fr;
        const float bb = bo[o];
        #pragma unroll
        for (int i = 0; i < 2; ++i)
            #pragma unroll
            for (int rg = 0; rg < 4; ++rg) {
                const int t = tm0 + wm + i*16 + quad*4 + rg;
                Y[(size_t)t*HID + o] = acc[i][j][rg] + bb;
            }
    }
}

// ---------------------------------------------------------------------------
// Launch.  Workspace (ushort units, 117 MB):
//   Qb,Kb f16 [B,H,S,D]; Vb f16 [B,H,D,S'] (sigma-permuted)
//   Of f16 [t][HID] token-major (attn output)
//   Xh f16; Wq/Wk/Wv/Wo f16
// ---------------------------------------------------------------------------
extern "C" void kernel_launch(void* const* d_in, const int* in_sizes, int n_in,
                              void* d_out, int out_size, void* d_ws, size_t ws_size,
                              hipStream_t stream)
{
    const float* X  = (const float*)d_in[0];
    const float* wq = (const float*)d_in[1];
    const float* bq = (const float*)d_in[2];
    const float* wk = (const float*)d_in[3];
    const float* bk = (const float*)d_in[4];
    const float* wv = (const float*)d_in[5];
    const float* bv = (const float*)d_in[6];
    const float* wo = (const float*)d_in[7];
    const float* bo = (const float*)d_in[8];
    float* Y = (float*)d_out;

    const size_t F  = (size_t)NT * HID;    // 8,388,608
    const size_t Wn = (size_t)HID * HID;   // 4,194,304

    unsigned short* Qb  = (unsigned short*)d_ws;
    unsigned short* Kb  = Qb  + F;
    unsigned short* Vb  = Kb  + F;     // [B,H,D,S'] permuted
    unsigned short* Of  = Vb  + F;     // token-major [t][HID]
    unsigned short* Xh  = Of  + F;
    unsigned short* Wqh = Xh  + F;
    unsigned short* Wkh = Wqh + Wn;
    unsigned short* Wvh = Wkh + Wn;
    unsigned short* Woh = Wvh + Wn;

    const int n4x = (int)(F/4);    // 2,097,152
    const int n4w = (int)(Wn/4);   // 1,048,576

    cast_all<<<dim3((n4x + 255)/256, 5), 256, 0, stream>>>(
        X, wq, wk, wv, wo, Xh, Wqh, Wkh, Wvh, Woh, n4x, n4w);

    qkv_f16<<<dim3(HID/128, NT/128, 3), 256, 0, stream>>>(
        Xh, Wqh, Wkh, Wvh, bq, bk, bv, Qb, Kb, Vb);

    attn_mfma<<<dim3(512, 1, 1), 512, 0, stream>>>(Qb, Kb, Vb, Of);

    oproj_f16<<<dim3(HID/128, NT/64), 256, 0, stream>>>(Of, Woh, bo, Y);
}